// Round 1
// baseline (260.840 us; speedup 1.0000x reference)
//
#include <hip/hip_runtime.h>
#include <math.h>

// Problem constants (fixed shapes per reference)
constexpr int NPB = 15;   // NUM_PROB_BINS
constexpr int NC  = 8;    // NUM_CLASSES
constexpr int NNB = 9;    // NUM_NEIGHBOR_CLASSES (3x3)
constexpr int Bn  = 16;
constexpr int Hc  = 512;
constexpr int Wc  = 512;

// Tile: 32x8 outputs per 256-thread block, +1 halo ring
constexpr int TX = 32, TY = 8;
constexpr int HX = TX + 2;  // 34
constexpr int HY = TY + 2;  // 10

__global__ __launch_bounds__(256)
void nectar_kernel(const float* __restrict__ logits,
                   const float* __restrict__ vf,
                   float* __restrict__ out)
{
    __shared__ float sP[NC][HY][HX];            // halo softmax probs, 10880 B
    __shared__ float sVF[NC * NNB * NPB];       // calibration table, 4320 B

    const int tid = threadIdx.x;
    const int x0  = blockIdx.x * TX;
    const int y0  = blockIdx.y * TY;
    const int b   = blockIdx.z;

    // Stage val_freqs
    for (int i = tid; i < NC * NNB * NPB; i += 256) sVF[i] = vf[i];

    const size_t plane = (size_t)Hc * Wc;
    const float* src = logits + (size_t)b * NC * plane;

    // Softmax for every halo pixel (zero prob outside the image — matches
    // reduce_window's zero padding feeding the neighborhood sum).
    for (int i = tid; i < HX * HY; i += 256) {
        const int ly = i / HX;
        const int lx = i - ly * HX;
        const int gy = y0 + ly - 1;
        const int gx = x0 + lx - 1;
        if ((unsigned)gy < (unsigned)Hc && (unsigned)gx < (unsigned)Wc) {
            const float* p = src + (size_t)gy * Wc + gx;
            float v[NC];
            #pragma unroll
            for (int c = 0; c < NC; c++) v[c] = p[(size_t)c * plane];
            float m = v[0];
            #pragma unroll
            for (int c = 1; c < NC; c++) m = fmaxf(m, v[c]);
            // Correctly-rounded fp32 exp via double; sequential fp32 sum
            // (numpy reduces a non-inner axis sequentially, not pairwise).
            float e[NC];
            float S = 0.0f;
            #pragma unroll
            for (int c = 0; c < NC; c++) {
                float d = v[c] - m;                 // exact fp32 op order
                e[c] = (float)exp((double)d);       // correctly-rounded fp32 exp
                S = S + e[c];                       // sequential accumulation
            }
            #pragma unroll
            for (int c = 0; c < NC; c++) sP[c][ly][lx] = e[c] / S;  // fp32 div
        } else {
            #pragma unroll
            for (int c = 0; c < NC; c++) sP[c][ly][lx] = 0.0f;
        }
    }
    __syncthreads();

    const int lx = tid & (TX - 1);
    const int ly = tid >> 5;
    const int gx = x0 + lx;
    const int gy = y0 + ly;

    float cal[NC];
    float s = 0.0f;
    #pragma unroll
    for (int c = 0; c < NC; c++) {
        // 3x3 neighborhood sum, sequential fp32 adds in (dy,dx) row-major
        // order (zero-padded terms are exact no-ops).
        float acc = 0.0f;
        #pragma unroll
        for (int dy = 0; dy < 3; dy++) {
            #pragma unroll
            for (int dx = 0; dx < 3; dx++) {
                acc = acc + sP[c][ly + dy][lx + dx];
            }
        }
        float nm = acc / 9.0f;                      // true fp32 division
        int lb = (int)floorf(nm * 9.0f);
        lb = lb < 0 ? 0 : (lb > NNB - 1 ? NNB - 1 : lb);
        float pcv = sP[c][ly + 1][lx + 1];
        int pb = (int)floorf(pcv * 15.0f);
        pb = pb < 0 ? 0 : (pb > NPB - 1 ? NPB - 1 : pb);
        cal[c] = sVF[(c * NNB + lb) * NPB + pb];
        s = s + cal[c];                             // sequential class sum
    }
    if (s == 0.0f) s = 1.0f;

    float* dst = out + (size_t)b * NC * plane + (size_t)gy * Wc + gx;
    #pragma unroll
    for (int c = 0; c < NC; c++) dst[(size_t)c * plane] = cal[c] / s;
}

extern "C" void kernel_launch(void* const* d_in, const int* in_sizes, int n_in,
                              void* d_out, int out_size, void* d_ws, size_t ws_size,
                              hipStream_t stream) {
    const float* logits = (const float*)d_in[0];
    const float* vf     = (const float*)d_in[1];
    float* out          = (float*)d_out;

    dim3 grid(Wc / TX, Hc / TY, Bn);   // (16, 64, 16)
    dim3 block(256);
    nectar_kernel<<<grid, block, 0, stream>>>(logits, vf, out);
}

// Round 2
// 255.815 us; speedup vs baseline: 1.0196x; 1.0196x over previous
//
#include <hip/hip_runtime.h>
#include <math.h>

// Problem constants (fixed shapes per reference)
constexpr int NPB = 15;   // NUM_PROB_BINS
constexpr int NC  = 8;    // NUM_CLASSES
constexpr int NNB = 9;    // NUM_NEIGHBOR_CLASSES (3x3)
constexpr int Bn  = 16;
constexpr int Hc  = 512;
constexpr int Wc  = 512;

// Tile: 32x16 outputs per 256-thread block, +1 halo ring.
// Each thread produces 2 vertically-adjacent outputs (shares 2 of 4 window rows).
constexpr int TX = 32, TY = 16;
constexpr int HX = TX + 2;  // 34
constexpr int HY = TY + 2;  // 18
constexpr int NT = 256;

// Correctly-rounded (to fp32) exp for d <= 0, |d| < ~600.
// Half-octave range reduction: k = rint(d * 2*log2e), r = d - k*ln2/2,
// exp(d) = 2^(k>>1) * (sqrt2 if k odd) * Taylor9(r), |r| <= ln2/4 = 0.1733.
// Poly rel err ~7e-15 -> non-CR probability ~2e-7 per call. Replaces OCML
// exp(double) (~40+ fp64 ops w/ special-case branches) with ~13 fp64 ops.
__device__ __forceinline__ float exp_f32_cr(float df) {
    const double d  = (double)df;
    const double TWO_LOG2E  = 2.8853900817779268;       // 2*log2(e)
    const double NLN2_2_HI  = -0.34657359018456190824;  // -(ln2_hi/2), 26-bit
    const double NLN2_2_LO  = -9.5410746463529385e-11;  // -(ln2_lo/2)
    double t  = d * TWO_LOG2E;
    double kd = rint(t);
    int    k  = (int)kd;
    double r  = fma(kd, NLN2_2_HI, d);
    r = fma(kd, NLN2_2_LO, r);
    // Taylor degree 9 (Horner), coefficients 1/i!
    double p = 2.7557319223985893e-6;
    p = fma(p, r, 2.4801587301587302e-5);
    p = fma(p, r, 1.9841269841269841e-4);
    p = fma(p, r, 1.3888888888888889e-3);
    p = fma(p, r, 8.3333333333333333e-3);
    p = fma(p, r, 4.1666666666666664e-2);
    p = fma(p, r, 1.6666666666666666e-1);
    p = fma(p, r, 0.5);
    p = fma(p, r, 1.0);
    p = fma(p, r, 1.0);
    // * sqrt2 if k odd (k may be negative: k&1 and k>>1 are floor-consistent)
    double sc = (k & 1) ? 1.4142135623730951 : 1.0;
    double v  = p * sc;
    // ldexp by k>>1 via exponent add (v in [0.7,1.5], k>>1 > -300: stays normal)
    long long bits = __double_as_longlong(v) + ((long long)(k >> 1) << 52);
    return (float)__longlong_as_double(bits);
}

__global__ __launch_bounds__(NT)
void nectar_kernel(const float* __restrict__ logits,
                   const float* __restrict__ vf,
                   float* __restrict__ out)
{
    __shared__ float sP[NC][HY][HX];        // halo softmax probs: 19584 B
    __shared__ float sVF[NC * NNB * NPB];   // calibration table:   4320 B

    const int tid = threadIdx.x;
    const int x0  = blockIdx.x * TX;
    const int y0  = blockIdx.y * TY;
    const int b   = blockIdx.z;

    for (int i = tid; i < NC * NNB * NPB; i += NT) sVF[i] = vf[i];

    const size_t plane = (size_t)Hc * Wc;
    const float* src = logits + (size_t)b * NC * plane;

    // Softmax for every halo pixel (zero prob outside image = reduce_window's
    // zero padding). All fp32 op order matches the reference sequence.
    for (int i = tid; i < HX * HY; i += NT) {
        const int ly = i / HX;
        const int lx = i - ly * HX;
        const int gy = y0 + ly - 1;
        const int gx = x0 + lx - 1;
        if ((unsigned)gy < (unsigned)Hc && (unsigned)gx < (unsigned)Wc) {
            const float* p = src + (size_t)gy * Wc + gx;
            float v[NC];
            #pragma unroll
            for (int c = 0; c < NC; c++) v[c] = p[(size_t)c * plane];
            float m = v[0];
            #pragma unroll
            for (int c = 1; c < NC; c++) m = fmaxf(m, v[c]);
            float S = 0.0f;
            #pragma unroll
            for (int c = 0; c < NC; c++) {
                v[c] = exp_f32_cr(v[c] - m);   // CR fp32 exp
                S = S + v[c];                   // sequential accumulation
            }
            #pragma unroll
            for (int c = 0; c < NC; c++) sP[c][ly][lx] = v[c] / S;  // IEEE div
        } else {
            #pragma unroll
            for (int c = 0; c < NC; c++) sP[c][ly][lx] = 0.0f;
        }
    }
    __syncthreads();

    // Each thread: outputs (lx, oy0) and (lx, oy0+1); window rows oy0..oy0+3.
    const int lx  = tid & (TX - 1);
    const int lyg = tid >> 5;
    const int oy0 = lyg * 2;
    const int gx  = x0 + lx;
    const int gy0 = y0 + oy0;

    float cal0[NC], cal1[NC];
    float s0 = 0.0f, s1 = 0.0f;
    #pragma unroll
    for (int c = 0; c < NC; c++) {
        // 4 window rows x 3 cols; rows 1-2 shared between the two outputs.
        float r0a = sP[c][oy0 + 0][lx], r0b = sP[c][oy0 + 0][lx + 1], r0c = sP[c][oy0 + 0][lx + 2];
        float r1a = sP[c][oy0 + 1][lx], r1b = sP[c][oy0 + 1][lx + 1], r1c = sP[c][oy0 + 1][lx + 2];
        float r2a = sP[c][oy0 + 2][lx], r2b = sP[c][oy0 + 2][lx + 1], r2c = sP[c][oy0 + 2][lx + 2];
        float r3a = sP[c][oy0 + 3][lx], r3b = sP[c][oy0 + 3][lx + 1], r3c = sP[c][oy0 + 3][lx + 2];
        // Strict left-to-right sequential add chains (row-major (dy,dx) order).
        float a0 = ((((((((r0a + r0b) + r0c) + r1a) + r1b) + r1c) + r2a) + r2b) + r2c);
        float a1 = ((((((((r1a + r1b) + r1c) + r2a) + r2b) + r2c) + r3a) + r3b) + r3c);

        float nm0 = a0 / 9.0f;                    // true fp32 division
        float nm1 = a1 / 9.0f;
        int lb0 = (int)floorf(nm0 * 9.0f);
        int lb1 = (int)floorf(nm1 * 9.0f);
        lb0 = lb0 < 0 ? 0 : (lb0 > NNB - 1 ? NNB - 1 : lb0);
        lb1 = lb1 < 0 ? 0 : (lb1 > NNB - 1 ? NNB - 1 : lb1);
        int pb0 = (int)floorf(r1b * 15.0f);       // center prob of output 0
        int pb1 = (int)floorf(r2b * 15.0f);       // center prob of output 1
        pb0 = pb0 < 0 ? 0 : (pb0 > NPB - 1 ? NPB - 1 : pb0);
        pb1 = pb1 < 0 ? 0 : (pb1 > NPB - 1 ? NPB - 1 : pb1);
        cal0[c] = sVF[(c * NNB + lb0) * NPB + pb0];
        cal1[c] = sVF[(c * NNB + lb1) * NPB + pb1];
        s0 = s0 + cal0[c];                        // sequential class sum
        s1 = s1 + cal1[c];
    }
    if (s0 == 0.0f) s0 = 1.0f;
    if (s1 == 0.0f) s1 = 1.0f;

    float* dst = out + (size_t)b * NC * plane + (size_t)gy0 * Wc + gx;
    #pragma unroll
    for (int c = 0; c < NC; c++) {
        dst[(size_t)c * plane]      = cal0[c] / s0;   // IEEE div
        dst[(size_t)c * plane + Wc] = cal1[c] / s1;
    }
}

extern "C" void kernel_launch(void* const* d_in, const int* in_sizes, int n_in,
                              void* d_out, int out_size, void* d_ws, size_t ws_size,
                              hipStream_t stream) {
    const float* logits = (const float*)d_in[0];
    const float* vf     = (const float*)d_in[1];
    float* out          = (float*)d_out;

    dim3 grid(Wc / TX, Hc / TY, Bn);   // (16, 32, 16)
    dim3 block(NT);
    nectar_kernel<<<grid, block, 0, stream>>>(logits, vf, out);
}

// Round 3
// 249.148 us; speedup vs baseline: 1.0469x; 1.0268x over previous
//
#include <hip/hip_runtime.h>
#include <math.h>

// Problem constants (fixed shapes per reference)
constexpr int NPB = 15;   // NUM_PROB_BINS
constexpr int NC  = 8;    // NUM_CLASSES
constexpr int NNB = 9;    // NUM_NEIGHBOR_CLASSES (3x3)
constexpr int Bn  = 16;
constexpr int Hc  = 512;
constexpr int Wc  = 512;

// Tile: 32x16 outputs per 256-thread block, +1 halo ring.
constexpr int TX = 32, TY = 16;
constexpr int HX = TX + 2;  // 34
constexpr int HY = TY + 2;  // 18
constexpr int NT = 256;

// fp32-correctly-rounded-almost-always exp for d in [-600, 0].
// Half-octave reduction, single-constant (|k|<=~1800 here |k|<=30 so
// kd*ulp(ln2/2) <= 8e-16 rel — no hi/lo split needed). Degree-8 Taylor on
// |r| <= ln2/4: rel err 3.7e-13 -> non-CR fraction q ~ 1e-5 -> expected
// bin flips ~3e-4 across all 357M calls. ~13 fp64-class ops.
__device__ __forceinline__ float exp_f32_cr(float df) {
    const double d = (double)df;
    double t  = d * 2.8853900817779268;            // 2*log2(e)
    double kd = rint(t);
    int    k  = (int)kd;
    double r  = fma(kd, -0.34657359027997265, d);  // nearest-double -(ln2/2)
    double p = 2.48015873015873016e-5;             // 1/8!
    p = fma(p, r, 1.98412698412698413e-4);
    p = fma(p, r, 1.38888888888888889e-3);
    p = fma(p, r, 8.33333333333333333e-3);
    p = fma(p, r, 4.16666666666666666e-2);
    p = fma(p, r, 1.66666666666666667e-1);
    p = fma(p, r, 0.5);
    p = fma(p, r, 1.0);
    p = fma(p, r, 1.0);
    double v = (k & 1) ? p * 1.4142135623730951 : p;
    // ldexp by k>>1 via exponent add (v in [0.7,1.5], stays normal)
    long long bits = __double_as_longlong(v) + ((long long)(k >> 1) << 52);
    return (float)__longlong_as_double(bits);
}

// Reciprocal accurate to ~1 ulp of double: v_rcp_f32 seed + 2 fp64 Newton
// iterations. fl32(x * rcp64(s)) differs from the CR fp32 divide fl32(x/s)
// with probability ~2^-29 — statistically zero bin flips.
__device__ __forceinline__ double rcp64(float s) {
    double dS = (double)s;
    double r  = (double)__builtin_amdgcn_rcpf(s);
    r = r * fma(-dS, r, 2.0);
    r = r * fma(-dS, r, 2.0);
    return r;
}

__global__ __launch_bounds__(NT)
void nectar_kernel(const float* __restrict__ logits,
                   const float* __restrict__ vf,
                   float* __restrict__ out)
{
    __shared__ float sP[NC][HY][HX];        // halo softmax probs: 19584 B
    __shared__ float sVF[NC * NNB * NPB];   // calibration table:   4320 B

    const int tid = threadIdx.x;
    const int x0  = blockIdx.x * TX;
    const int y0  = blockIdx.y * TY;
    const int b   = blockIdx.z;

    for (int i = tid; i < NC * NNB * NPB; i += NT) sVF[i] = vf[i];

    const size_t plane = (size_t)Hc * Wc;
    const float* src = logits + (size_t)b * NC * plane;

    // Softmax for every halo pixel (zero prob outside image = reduce_window's
    // zero padding). fp32 op ORDER matches the reference sequence; the /S is
    // a double-reciprocal multiply (see rcp64 note).
    for (int i = tid; i < HX * HY; i += NT) {
        const int ly = i / HX;
        const int lx = i - ly * HX;
        const int gy = y0 + ly - 1;
        const int gx = x0 + lx - 1;
        if ((unsigned)gy < (unsigned)Hc && (unsigned)gx < (unsigned)Wc) {
            const float* p = src + (size_t)gy * Wc + gx;
            float v[NC];
            #pragma unroll
            for (int c = 0; c < NC; c++) v[c] = p[(size_t)c * plane];
            float m = v[0];
            #pragma unroll
            for (int c = 1; c < NC; c++) m = fmaxf(m, v[c]);
            float S = 0.0f;
            #pragma unroll
            for (int c = 0; c < NC; c++) {
                v[c] = exp_f32_cr(v[c] - m);
                S = S + v[c];                   // sequential accumulation
            }
            double rS = rcp64(S);
            #pragma unroll
            for (int c = 0; c < NC; c++)
                sP[c][ly][lx] = (float)((double)v[c] * rS);
        } else {
            #pragma unroll
            for (int c = 0; c < NC; c++) sP[c][ly][lx] = 0.0f;
        }
    }
    __syncthreads();

    // Each thread: outputs (lx, oy0) and (lx, oy0+1); window rows oy0..oy0+3.
    const int lx  = tid & (TX - 1);
    const int lyg = tid >> 5;
    const int oy0 = lyg * 2;
    const int gx  = x0 + lx;
    const int gy0 = y0 + oy0;

    const double C9 = 0.1111111111111111111;    // nearest double to 1/9

    float cal0[NC], cal1[NC];
    float s0 = 0.0f, s1 = 0.0f;
    #pragma unroll
    for (int c = 0; c < NC; c++) {
        float r0a = sP[c][oy0 + 0][lx], r0b = sP[c][oy0 + 0][lx + 1], r0c = sP[c][oy0 + 0][lx + 2];
        float r1a = sP[c][oy0 + 1][lx], r1b = sP[c][oy0 + 1][lx + 1], r1c = sP[c][oy0 + 1][lx + 2];
        float r2a = sP[c][oy0 + 2][lx], r2b = sP[c][oy0 + 2][lx + 1], r2c = sP[c][oy0 + 2][lx + 2];
        float r3a = sP[c][oy0 + 3][lx], r3b = sP[c][oy0 + 3][lx + 1], r3c = sP[c][oy0 + 3][lx + 2];
        // Strict left-to-right sequential add chains (row-major (dy,dx) order).
        float a0 = ((((((((r0a + r0b) + r0c) + r1a) + r1b) + r1c) + r2a) + r2b) + r2c);
        float a1 = ((((((((r1a + r1b) + r1c) + r2a) + r2b) + r2c) + r3a) + r3b) + r3c);

        // nm = fl32(a/9): double-multiply path, differs from CR divide with
        // probability ~3e-9 (rel err 1.7e-16).
        float nm0 = (float)((double)a0 * C9);
        float nm1 = (float)((double)a1 * C9);
        int lb0 = (int)(nm0 * 9.0f);            // trunc == floor (nm >= 0)
        int lb1 = (int)(nm1 * 9.0f);
        lb0 = lb0 > NNB - 1 ? NNB - 1 : lb0;
        lb1 = lb1 > NNB - 1 ? NNB - 1 : lb1;
        int pb0 = (int)(r1b * 15.0f);           // center prob of output 0
        int pb1 = (int)(r2b * 15.0f);           // center prob of output 1
        pb0 = pb0 > NPB - 1 ? NPB - 1 : pb0;
        pb1 = pb1 > NPB - 1 ? NPB - 1 : pb1;
        cal0[c] = sVF[(c * NNB + lb0) * NPB + pb0];
        cal1[c] = sVF[(c * NNB + lb1) * NPB + pb1];
        s0 = s0 + cal0[c];                      // sequential class sum
        s1 = s1 + cal1[c];
    }
    if (s0 == 0.0f) s0 = 1.0f;
    if (s1 == 0.0f) s1 = 1.0f;

    // Final normalize is NOT bin-critical: fp32 rcp + 1 Newton (rel err
    // ~1.2e-7 << 1.55e-2 threshold) replaces 16 IEEE divides.
    float q0 = __builtin_amdgcn_rcpf(s0);
    q0 = q0 * fmaf(-s0, q0, 2.0f);
    float q1 = __builtin_amdgcn_rcpf(s1);
    q1 = q1 * fmaf(-s1, q1, 2.0f);

    float* dst = out + (size_t)b * NC * plane + (size_t)gy0 * Wc + gx;
    #pragma unroll
    for (int c = 0; c < NC; c++) {
        dst[(size_t)c * plane]      = cal0[c] * q0;
        dst[(size_t)c * plane + Wc] = cal1[c] * q1;
    }
}

extern "C" void kernel_launch(void* const* d_in, const int* in_sizes, int n_in,
                              void* d_out, int out_size, void* d_ws, size_t ws_size,
                              hipStream_t stream) {
    const float* logits = (const float*)d_in[0];
    const float* vf     = (const float*)d_in[1];
    float* out          = (float*)d_out;

    dim3 grid(Wc / TX, Hc / TY, Bn);   // (16, 32, 16)
    dim3 block(NT);
    nectar_kernel<<<grid, block, 0, stream>>>(logits, vf, out);
}

// Round 4
// 239.643 us; speedup vs baseline: 1.0885x; 1.0397x over previous
//
#include <hip/hip_runtime.h>
#include <math.h>

// Problem constants (fixed shapes per reference)
constexpr int NPB = 15;   // NUM_PROB_BINS
constexpr int NC  = 8;    // NUM_CLASSES
constexpr int NNB = 9;    // NUM_NEIGHBOR_CLASSES (3x3)
constexpr int Bn  = 16;
constexpr int Hc  = 512;
constexpr int Wc  = 512;

// Tile: 32x32 outputs per 512-thread block, +1 halo ring.
// Halo redundancy 34*34/1024 = 1.13 (was 1.196 at 32x16).
constexpr int TX = 32, TY = 32;
constexpr int HX = TX + 2;  // 34
constexpr int HY = TY + 2;  // 34
constexpr int NT = 512;
constexpr int GX = Wc / TX;           // 16
constexpr int GY = Hc / TY;           // 16
constexpr int NBLK = GX * GY * Bn;    // 4096

// fp32-correctly-rounded-almost-always exp for d in [-90, 0].
// Half-octave reduction, single constant (|k|<=260 -> kd*ulp(ln2/2) < 6e-15
// rel). Degree-8 Taylor on |r| <= ln2/4: rel err 3.7e-13 -> non-CR fraction
// ~1e-5 -> expected bin flips ~1e-4 over all 40M calls. Validated R2/R3:
// absmax stayed at the bf16 comparison floor (no flips).
__device__ __forceinline__ float exp_f32_cr(float df) {
    const double d = (double)df;
    double t  = d * 2.8853900817779268;            // 2*log2(e)
    double kd = rint(t);
    int    k  = (int)kd;
    double r  = fma(kd, -0.34657359027997265, d);  // nearest-double -(ln2/2)
    double p = 2.48015873015873016e-5;             // 1/8!
    p = fma(p, r, 1.98412698412698413e-4);
    p = fma(p, r, 1.38888888888888889e-3);
    p = fma(p, r, 8.33333333333333333e-3);
    p = fma(p, r, 4.16666666666666666e-2);
    p = fma(p, r, 1.66666666666666667e-1);
    p = fma(p, r, 0.5);
    p = fma(p, r, 1.0);
    p = fma(p, r, 1.0);
    double v = (k & 1) ? p * 1.4142135623730951 : p;
    // ldexp by k>>1 via exponent add (v in [0.7,1.5], stays normal)
    long long bits = __double_as_longlong(v) + ((long long)(k >> 1) << 52);
    return (float)__longlong_as_double(bits);
}

// Reciprocal to ~1 ulp of double: rcp_f32 seed + 2 fp64 Newton iters.
// fl32(x * rcp64(s)) != fl32(x/s) with probability ~2^-29 — no bin flips.
__device__ __forceinline__ double rcp64(float s) {
    double dS = (double)s;
    double r  = (double)__builtin_amdgcn_rcpf(s);
    r = r * fma(-dS, r, 2.0);
    r = r * fma(-dS, r, 2.0);
    return r;
}

__global__ __launch_bounds__(NT)
void nectar_kernel(const float* __restrict__ logits,
                   const float* __restrict__ vf,
                   float* __restrict__ out)
{
    __shared__ float sP[NC][HY][HX];        // halo softmax probs: 36992 B
    __shared__ float sVF[NC * NNB * NPB];   // calibration table:   4320 B
    // total 41312 B -> 3 blocks/CU, 24 waves/CU

    const int tid = threadIdx.x;

    // XCD swizzle: hw dispatch is ~round-robin over 8 XCDs by block index.
    // Remap so each XCD owns 32 CONSECUTIVE semantic tiles (= 2 full tile-
    // rows of one image): halo rows + tile-edge partial cache lines are then
    // re-read from that XCD's own L2 instead of HBM. Pure perf heuristic —
    // correctness doesn't depend on the mapping.
    const int h    = blockIdx.x;            // 0..4095
    const int sg   = h >> 8;                // supergroup of 256
    const int xcd  = h & 7;
    const int slot = (h >> 3) & 31;
    const int sem  = (sg << 8) + (xcd << 5) + slot;

    const int bx = sem & (GX - 1);
    const int by = (sem >> 4) & (GY - 1);
    const int b  = sem >> 8;
    const int x0 = bx * TX;
    const int y0 = by * TY;

    for (int i = tid; i < NC * NNB * NPB; i += NT) sVF[i] = vf[i];

    const size_t plane = (size_t)Hc * Wc;
    const float* src = logits + (size_t)b * NC * plane;

    // Phase 1: softmax for every halo pixel (zero prob outside image =
    // reduce_window's zero padding). fp32 op ORDER matches the reference.
    for (int i = tid; i < HX * HY; i += NT) {
        const int ly = i / HX;
        const int lx = i - ly * HX;
        const int gy = y0 + ly - 1;
        const int gx = x0 + lx - 1;
        if ((unsigned)gy < (unsigned)Hc && (unsigned)gx < (unsigned)Wc) {
            const float* p = src + (size_t)gy * Wc + gx;
            float v[NC];
            #pragma unroll
            for (int c = 0; c < NC; c++) v[c] = p[(size_t)c * plane];
            float m = v[0];
            #pragma unroll
            for (int c = 1; c < NC; c++) m = fmaxf(m, v[c]);
            float S = 0.0f;
            #pragma unroll
            for (int c = 0; c < NC; c++) {
                v[c] = exp_f32_cr(v[c] - m);
                S = S + v[c];                   // sequential accumulation
            }
            double rS = rcp64(S);
            #pragma unroll
            for (int c = 0; c < NC; c++)
                sP[c][ly][lx] = (float)((double)v[c] * rS);
        } else {
            #pragma unroll
            for (int c = 0; c < NC; c++) sP[c][ly][lx] = 0.0f;
        }
    }
    __syncthreads();

    // Phase 2: each thread -> outputs (lx, oy0), (lx, oy0+1).
    const int lx  = tid & (TX - 1);
    const int oy0 = (tid >> 5) * 2;
    const int gx  = x0 + lx;
    const int gy0 = y0 + oy0;

    const double C9 = 0.1111111111111111111;    // nearest double to 1/9

    float cal0[NC], cal1[NC];
    float s0 = 0.0f, s1 = 0.0f;
    #pragma unroll
    for (int c = 0; c < NC; c++) {
        float r0a = sP[c][oy0 + 0][lx], r0b = sP[c][oy0 + 0][lx + 1], r0c = sP[c][oy0 + 0][lx + 2];
        float r1a = sP[c][oy0 + 1][lx], r1b = sP[c][oy0 + 1][lx + 1], r1c = sP[c][oy0 + 1][lx + 2];
        float r2a = sP[c][oy0 + 2][lx], r2b = sP[c][oy0 + 2][lx + 1], r2c = sP[c][oy0 + 2][lx + 2];
        float r3a = sP[c][oy0 + 3][lx], r3b = sP[c][oy0 + 3][lx + 1], r3c = sP[c][oy0 + 3][lx + 2];
        // Strict left-to-right sequential add chains (row-major (dy,dx)
        // order) — reassociation would flip bins, order is sacred.
        float a0 = ((((((((r0a + r0b) + r0c) + r1a) + r1b) + r1c) + r2a) + r2b) + r2c);
        float a1 = ((((((((r1a + r1b) + r1c) + r2a) + r2b) + r2c) + r3a) + r3b) + r3c);

        float nm0 = (float)((double)a0 * C9);   // fl32(a/9) via double mul
        float nm1 = (float)((double)a1 * C9);
        int lb0 = (int)(nm0 * 9.0f);            // trunc == floor (nm >= 0)
        int lb1 = (int)(nm1 * 9.0f);
        lb0 = lb0 > NNB - 1 ? NNB - 1 : lb0;
        lb1 = lb1 > NNB - 1 ? NNB - 1 : lb1;
        int pb0 = (int)(r1b * 15.0f);
        int pb1 = (int)(r2b * 15.0f);
        pb0 = pb0 > NPB - 1 ? NPB - 1 : pb0;
        pb1 = pb1 > NPB - 1 ? NPB - 1 : pb1;
        cal0[c] = sVF[(c * NNB + lb0) * NPB + pb0];
        cal1[c] = sVF[(c * NNB + lb1) * NPB + pb1];
        s0 = s0 + cal0[c];                      // sequential class sum
        s1 = s1 + cal1[c];
    }
    if (s0 == 0.0f) s0 = 1.0f;
    if (s1 == 0.0f) s1 = 1.0f;

    // Final normalize is NOT bin-critical (bf16-floor comparison): fp32
    // rcp + 1 Newton, rel err ~1e-7 << threshold.
    float q0 = __builtin_amdgcn_rcpf(s0);
    q0 = q0 * fmaf(-s0, q0, 2.0f);
    float q1 = __builtin_amdgcn_rcpf(s1);
    q1 = q1 * fmaf(-s1, q1, 2.0f);

    float* dst = out + (size_t)b * NC * plane + (size_t)gy0 * Wc + gx;
    #pragma unroll
    for (int c = 0; c < NC; c++) {
        dst[(size_t)c * plane]      = cal0[c] * q0;
        dst[(size_t)c * plane + Wc] = cal1[c] * q1;
    }
}

extern "C" void kernel_launch(void* const* d_in, const int* in_sizes, int n_in,
                              void* d_out, int out_size, void* d_ws, size_t ws_size,
                              hipStream_t stream) {
    const float* logits = (const float*)d_in[0];
    const float* vf     = (const float*)d_in[1];
    float* out          = (float*)d_out;

    nectar_kernel<<<dim3(NBLK), dim3(NT), 0, stream>>>(logits, vf, out);
}